// Round 11
// baseline (294.927 us; speedup 1.0000x reference)
//
#include <hip/hip_runtime.h>
#include <hip/hip_bf16.h>

#define NN 100000
#define NE 600000
#define NBLK 98            // ceil(NN/1024) for the scan
#define MPAD 100096        // 782 * 128

typedef __attribute__((ext_vector_type(4))) int   i32x4;
typedef __attribute__((ext_vector_type(4))) float f32x4;

// ---------- helpers ----------
__device__ __forceinline__ float b2f(unsigned short u) {
  unsigned int v = ((unsigned int)u) << 16;
  return __uint_as_float(v);
}
__device__ __forceinline__ unsigned short f2b(float f) {
  __hip_bfloat16 h = __float2bfloat16(f);  // RNE
  return *reinterpret_cast<unsigned short*>(&h);
}
__device__ __forceinline__ float elu(float v) {
  return v > 0.0f ? v : (expf(v) - 1.0f);
}
__device__ __forceinline__ void gload_lds16(const void* g, void* l) {
  __builtin_amdgcn_global_load_lds(
      (const __attribute__((address_space(1))) void*)g,
      (__attribute__((address_space(3))) void*)l, 16, 0, 0);
}
__device__ __forceinline__ f32x4 mfma16(i32x4 a, i32x4 b, f32x4 c) {
  asm volatile("v_mfma_f32_16x16x32_bf16 %0, %1, %2, %0"
               : "+v"(c) : "v"(a), "v"(b));
  return c;
}

// packed fragment layouts (see R9): A-operand [ROWS x K]:
//   off(row,k) = (row/128)*(128*K) + (k/32)*4096 + ((row/16)%8)*512
//              + ((k/8)%4)*128 + (row%16)*8 + k%8
// B-operand [NC cols x K]:
//   off(col,k) = (k/32)*(NC*32) + (col/16)*512 + ((k/8)%4)*128 + (col%16)*8 + k%8

// ================= CSR build (by destination) =================
__global__ __launch_bounds__(256) void hist_kernel(
    const int* __restrict__ ei, int* __restrict__ deg) {
  const int* dst = ei + NE;
  int i = blockIdx.x * 256 + threadIdx.x;
  int n = gridDim.x * 256;
  for (int e = i; e < NE; e += n) atomicAdd(&deg[dst[e]], 1);
}

__global__ __launch_bounds__(256) void scan1_kernel(
    const int* __restrict__ deg, int* __restrict__ row, int* __restrict__ aux) {
  __shared__ int sd[256];
  int b = blockIdx.x, t = threadIdx.x;
  int base = b * 1024 + t * 4;
  int v0 = (base + 0 < NN) ? deg[base + 0] : 0;
  int v1 = (base + 1 < NN) ? deg[base + 1] : 0;
  int v2 = (base + 2 < NN) ? deg[base + 2] : 0;
  int v3 = (base + 3 < NN) ? deg[base + 3] : 0;
  int s = v0 + v1 + v2 + v3;
  sd[t] = s;
  __syncthreads();
  for (int off = 1; off < 256; off <<= 1) {
    int tmp = (t >= off) ? sd[t - off] : 0;
    __syncthreads();
    sd[t] += tmp;
    __syncthreads();
  }
  int excl = sd[t] - s;
  if (base + 0 < NN) row[base + 0] = excl;
  if (base + 1 < NN) row[base + 1] = excl + v0;
  if (base + 2 < NN) row[base + 2] = excl + v0 + v1;
  if (base + 3 < NN) row[base + 3] = excl + v0 + v1 + v2;
  if (t == 255) aux[b] = sd[t];
}

__global__ __launch_bounds__(256) void scan2_kernel(int* __restrict__ aux) {
  __shared__ int sd[256];
  int t = threadIdx.x;
  int v = (t < NBLK) ? aux[t] : 0;
  sd[t] = v;
  __syncthreads();
  for (int off = 1; off < 256; off <<= 1) {
    int tmp = (t >= off) ? sd[t - off] : 0;
    __syncthreads();
    sd[t] += tmp;
    __syncthreads();
  }
  if (t < NBLK) aux[t] = sd[t] - v;
}

__global__ __launch_bounds__(256) void scan3_kernel(
    int* __restrict__ row, const int* __restrict__ aux) {
  int i = blockIdx.x * 256 + threadIdx.x;
  if (i < NN) row[i] += aux[i >> 10];
  if (i == 0) row[NN] = NE;
}

__global__ __launch_bounds__(256) void fill_kernel(
    const int* __restrict__ ei, const int* __restrict__ row,
    int* __restrict__ cur, int* __restrict__ eidx) {
  const int* src = ei;
  const int* dst = ei + NE;
  int i = blockIdx.x * 256 + threadIdx.x;
  int n = gridDim.x * 256;
  for (int e = i; e < NE; e += n) {
    int d = dst[e];
    int p = atomicAdd(&cur[d], 1);
    eidx[row[d] + p] = src[e];
  }
}

// ============ conversions ============
__global__ __launch_bounds__(256) void conv_x(
    const float* __restrict__ x, unsigned short* __restrict__ A1) {
  int i = blockIdx.x * 256 + threadIdx.x;  // float4 groups
  if (i >= NN * 32) return;
  int n = i >> 5, k4 = i & 31;
  float4 v = ((const float4*)(x + (size_t)n * 128))[k4];
  ushort4 o;
  o.x = f2b(v.x); o.y = f2b(v.y); o.z = f2b(v.z); o.w = f2b(v.w);
  ((ushort4*)(A1 + (size_t)n * 256 + 128))[k4] = o;
}

// weights -> PACKED fragment layout (B-operand form).
__global__ __launch_bounds__(256) void conv_w(
    const float* __restrict__ W1l, const float* __restrict__ W1r,
    const float* __restrict__ W2l, const float* __restrict__ W2r,
    const float* __restrict__ Wf1,
    unsigned short* __restrict__ W1b, unsigned short* __restrict__ W2b,
    unsigned short* __restrict__ Wf1b) {
  int g = blockIdx.x * 256 + threadIdx.x;
  const float* src;
  unsigned short* dst;
  int j, k, NC;
  if (g < 8192) {                       // W1b: 256 cols x K=256 = [W1l|W1r]
    j = g >> 5; k = (g & 31) * 8; NC = 256; dst = W1b;
    src = (k < 128) ? (W1l + (size_t)j * 128 + k)
                    : (W1r + (size_t)j * 128 + (k - 128));
  } else if (g < 24576) {               // W2b: 256 cols x K=512 = [W2l|W2r]
    int h = g - 8192; j = h >> 6; k = (h & 63) * 8; NC = 256; dst = W2b;
    src = (k < 256) ? (W2l + (size_t)j * 256 + k)
                    : (W2r + (size_t)j * 256 + (k - 256));
  } else if (g < 28672) {               // Wf1b: 128 cols x K=256
    int h = g - 24576; j = h >> 5; k = (h & 31) * 8; NC = 128; dst = Wf1b;
    src = Wf1 + (size_t)j * 256 + k;
  } else return;
  float4 v0 = *(const float4*)src;
  float4 v1 = *(const float4*)(src + 4);
  unsigned short o[8] = {f2b(v0.x), f2b(v0.y), f2b(v0.z), f2b(v0.w),
                         f2b(v1.x), f2b(v1.y), f2b(v1.z), f2b(v1.w)};
  size_t off = (size_t)(k >> 5) * (NC * 32) + (j >> 4) * 512 +
               ((k >> 3) & 3) * 128 + (j & 15) * 8;
  *(i32x4*)(dst + off) = *(i32x4*)o;
}

// ============ aggregation via CSR gather (row-major in/out, unchanged) ========
__global__ __launch_bounds__(256) void agg1_csr(
    unsigned short* __restrict__ A1, const int* __restrict__ row,
    const int* __restrict__ eidx) {
  int lane = threadIdx.x & 63;
  int n = (blockIdx.x * 256 + threadIdx.x) >> 6;
  if (n >= NN) return;
  int r0 = row[n], r1 = row[n + 1];
  float ax = 0.f, ay = 0.f;
  int e = r0;
  for (; e + 3 < r1; e += 4) {
    int s0 = eidx[e], s1 = eidx[e + 1], s2 = eidx[e + 2], s3 = eidx[e + 3];
    ushort2 a = ((const ushort2*)(A1 + (size_t)s0 * 256 + 128))[lane];
    ushort2 b = ((const ushort2*)(A1 + (size_t)s1 * 256 + 128))[lane];
    ushort2 c = ((const ushort2*)(A1 + (size_t)s2 * 256 + 128))[lane];
    ushort2 d = ((const ushort2*)(A1 + (size_t)s3 * 256 + 128))[lane];
    ax += (b2f(a.x) + b2f(b.x)) + (b2f(c.x) + b2f(d.x));
    ay += (b2f(a.y) + b2f(b.y)) + (b2f(c.y) + b2f(d.y));
  }
  for (; e < r1; ++e) {
    int s0 = eidx[e];
    ushort2 a = ((const ushort2*)(A1 + (size_t)s0 * 256 + 128))[lane];
    ax += b2f(a.x);
    ay += b2f(a.y);
  }
  float inv = 1.0f / (float)max(r1 - r0, 1);
  ushort2 o;
  o.x = f2b(ax * inv);
  o.y = f2b(ay * inv);
  ((ushort2*)(A1 + (size_t)n * 256))[lane] = o;
}

__global__ __launch_bounds__(256) void agg2_csr(
    unsigned short* __restrict__ A2, const int* __restrict__ row,
    const int* __restrict__ eidx) {
  int lane = threadIdx.x & 63;
  int n = (blockIdx.x * 256 + threadIdx.x) >> 6;
  if (n >= NN) return;
  int r0 = row[n], r1 = row[n + 1];
  float4 acc = make_float4(0.f, 0.f, 0.f, 0.f);
  int e = r0;
  for (; e + 3 < r1; e += 4) {
    int s0 = eidx[e], s1 = eidx[e + 1], s2 = eidx[e + 2], s3 = eidx[e + 3];
    ushort4 a = ((const ushort4*)(A2 + (size_t)s0 * 512 + 256))[lane];
    ushort4 b = ((const ushort4*)(A2 + (size_t)s1 * 512 + 256))[lane];
    ushort4 c = ((const ushort4*)(A2 + (size_t)s2 * 512 + 256))[lane];
    ushort4 d = ((const ushort4*)(A2 + (size_t)s3 * 512 + 256))[lane];
    acc.x += (b2f(a.x) + b2f(b.x)) + (b2f(c.x) + b2f(d.x));
    acc.y += (b2f(a.y) + b2f(b.y)) + (b2f(c.y) + b2f(d.y));
    acc.z += (b2f(a.z) + b2f(b.z)) + (b2f(c.z) + b2f(d.z));
    acc.w += (b2f(a.w) + b2f(b.w)) + (b2f(c.w) + b2f(d.w));
  }
  for (; e < r1; ++e) {
    int s0 = eidx[e];
    ushort4 a = ((const ushort4*)(A2 + (size_t)s0 * 512 + 256))[lane];
    acc.x += b2f(a.x);
    acc.y += b2f(a.y);
    acc.z += b2f(a.z);
    acc.w += b2f(a.w);
  }
  float inv = 1.0f / (float)max(r1 - r0, 1);
  ushort4 o;
  o.x = f2b(acc.x * inv);
  o.y = f2b(acc.y * inv);
  o.z = f2b(acc.z * inv);
  o.w = f2b(acc.w * inv);
  ((ushort4*)(A2 + (size_t)n * 512))[lane] = o;
}

// ===== MFMA GEMM: BM=128, BN=NF*16 (full width, no grid.y), BK=32, 2-buf ======
// R7 race-hardened schedule. 4 waves; wave w owns rows [m0+32w,+32) x all cols.
// NF=16: acc 128 regs (AGPR-backed), LDS 2x(8KB A + 16KB B)=48KB -> 3 blk/CU,
//        grid 782 ~= 1.0 round.  NF=8 (head): 32KB -> 4 blk/CU.
// B always packed; A packed iff AP. HPACK: EPI0 stores h2 in packed-A form.
template <int K, int APITCH, int NF, int EPI, int AP, int BNC, int HPACK>
__global__ __launch_bounds__(256, NF == 16 ? 3 : 4) void gemm_kernel(
    const unsigned short* __restrict__ A, const unsigned short* __restrict__ Wb,
    const float* __restrict__ bias, const float* __restrict__ w2,
    const float* __restrict__ bf2p,
    unsigned short* __restrict__ Hout, int HPITCH, int HOFF,
    float* __restrict__ out) {
  __shared__ unsigned short lA[2][4096];
  __shared__ unsigned short lB[2][NF * 512];
  int tid = threadIdx.x;
  int w = tid >> 6, lane = tid & 63;
  int lhi = lane >> 4, llo = lane & 15;
  int m0 = blockIdx.x * 128;
  int fb = lane * 8;  // fragment-local elem offset (16B/lane, bank-spread)

  f32x4 acc0[NF], acc1[NF];
#pragma unroll
  for (int n = 0; n < NF; ++n) { acc0[n] = (f32x4)0.f; acc1[n] = (f32x4)0.f; }

#define STAGE(t)                                                                \
  do {                                                                          \
    int _b = (t) & 1;                                                           \
    _Pragma("unroll")                                                           \
    for (int i = 0; i < 2; ++i) {                                               \
      int c = w * 2 + i;                                                        \
      const unsigned short* ga;                                                 \
      if constexpr (AP) {                                                       \
        ga = A + (size_t)(m0 >> 7) * (128 * K) + (size_t)(t) * 4096 +           \
             c * 512 + lane * 8;                                                \
      } else {                                                                  \
        ga = A + (size_t)(m0 + c * 16 + llo) * APITCH + (t) * 32 + lhi * 8;     \
      }                                                                         \
      gload_lds16(ga, &lA[_b][c * 512]);                                        \
    }                                                                           \
    _Pragma("unroll")                                                           \
    for (int i = 0; i < NF / 4; ++i) {                                          \
      int c = w * (NF / 4) + i;                                                 \
      const unsigned short* gb = Wb + (size_t)(t) * (BNC * 32) +                \
                                 c * 512 + lane * 8;                            \
      gload_lds16(gb, &lB[_b][c * 512]);                                        \
    }                                                                           \
  } while (0)

  constexpr int NSTEP = K / 32;
  STAGE(0);
  __builtin_amdgcn_sched_barrier(0);
  asm volatile("s_waitcnt vmcnt(0)" ::: "memory");
  __syncthreads();
  for (int t = 0; t < NSTEP; ++t) {
    if (t + 1 < NSTEP) STAGE(t + 1);
    const unsigned short* la = &lA[t & 1][0];
    const unsigned short* lb = &lB[t & 1][0];
    i32x4 a0 = *(const i32x4*)(la + (w * 2 + 0) * 512 + fb);
    i32x4 a1 = *(const i32x4*)(la + (w * 2 + 1) * 512 + fb);
#pragma unroll
    for (int n = 0; n < NF; ++n) {
      i32x4 b = *(const i32x4*)(lb + n * 512 + fb);
      acc0[n] = mfma16(a0, b, acc0[n]);
      acc1[n] = mfma16(a1, b, acc1[n]);
    }
    // pin all motion, then drain STAGE(t+1)'s DMA before the buffer handoff
    __builtin_amdgcn_sched_barrier(0);
    asm volatile("s_waitcnt vmcnt(0)" ::: "memory");
    __syncthreads();
  }
#undef STAGE
  asm volatile("s_nop 7\n\ts_nop 7");  // MFMA -> VALU read hazard

  if constexpr (EPI == 0) {
    float bv[NF];
#pragma unroll
    for (int n = 0; n < NF; ++n) bv[n] = bias[n * 16 + llo];
    // hoisted packed-store components: off = mb + cp[n] + (w*2+mi)*512 + (lhi*4+r)*8
    int cp[NF];
#pragma unroll
    for (int n = 0; n < NF; ++n) {
      int col = n * 16 + llo;
      cp[n] = (col >> 5) * 4096 + ((col >> 3) & 3) * 128 + (col & 7);
    }
    size_t mb = (size_t)(m0 >> 7) * 32768;
#pragma unroll
    for (int mi = 0; mi < 2; ++mi) {
#pragma unroll
      for (int n = 0; n < NF; ++n) {
        f32x4 av = mi ? acc1[n] : acc0[n];
#pragma unroll
        for (int r = 0; r < 4; ++r) {
          int R = m0 + (w * 2 + mi) * 16 + lhi * 4 + r;
          float v = elu(av[r] + bv[n]);
          if constexpr (HPACK) {
            Hout[mb + cp[n] + (w * 2 + mi) * 512 + (lhi * 4 + r) * 8] = f2b(v);
          } else {
            Hout[(size_t)R * HPITCH + HOFF + n * 16 + llo] = f2b(v);
          }
        }
      }
    }
  } else {
    float b1v[NF], w2v[NF];
#pragma unroll
    for (int n = 0; n < NF; ++n) {
      b1v[n] = bias[n * 16 + llo];
      w2v[n] = w2[n * 16 + llo];
    }
    float bf2v = bf2p[0];
#pragma unroll
    for (int mi = 0; mi < 2; ++mi) {
#pragma unroll
      for (int r = 0; r < 4; ++r) {
        float s = 0.f;
#pragma unroll
        for (int n = 0; n < NF; ++n) {
          f32x4 av = mi ? acc1[n] : acc0[n];
          s += fmaxf(av[r] + b1v[n], 0.f) * w2v[n];
        }
        s += __shfl_xor(s, 1);
        s += __shfl_xor(s, 2);
        s += __shfl_xor(s, 4);
        s += __shfl_xor(s, 8);
        int R = m0 + (w * 2 + mi) * 16 + lhi * 4 + r;
        if (llo == 0 && R < NN) out[R] = s + bf2v;
      }
    }
  }
}

extern "C" void kernel_launch(void* const* d_in, const int* in_sizes, int n_in,
                              void* d_out, int out_size, void* d_ws, size_t ws_size,
                              hipStream_t stream) {
  const float* x   = (const float*)d_in[0];
  const int*   ei  = (const int*)d_in[1];
  const float* W1l = (const float*)d_in[2];
  const float* b1  = (const float*)d_in[3];
  const float* W1r = (const float*)d_in[4];
  const float* W2l = (const float*)d_in[5];
  const float* b2  = (const float*)d_in[6];
  const float* W2r = (const float*)d_in[7];
  const float* Wf1 = (const float*)d_in[8];
  const float* bf1 = (const float*)d_in[9];
  const float* Wf2 = (const float*)d_in[10];
  const float* bf2 = (const float*)d_in[11];
  float* out = (float*)d_out;

  char* ws = (char*)d_ws;
  size_t o = 0;
  int* deg = (int*)(ws + o); o += 400384;   // zeroed each call
  int* cur = (int*)(ws + o); o += 400384;   // zeroed each call
  size_t zero_bytes = o;
  int* row  = (int*)(ws + o); o += 400640;  // NN+1
  int* aux  = (int*)(ws + o); o += 4096;
  int* eidx = (int*)(ws + o); o += 2400000;
  unsigned short* A1 = (unsigned short*)(ws + o); o += (size_t)MPAD * 256 * 2; // [mean1|x] row-major
  unsigned short* A2 = (unsigned short*)(ws + o); o += (size_t)MPAD * 512 * 2; // [mean2|h1] row-major
  unsigned short* h2 = (unsigned short*)(ws + o); o += (size_t)MPAD * 256 * 2; // PACKED
  unsigned short* W1b  = (unsigned short*)(ws + o); o += 131072;  // PACKED
  unsigned short* W2b  = (unsigned short*)(ws + o); o += 262144;  // PACKED
  unsigned short* Wf1b = (unsigned short*)(ws + o); o += 65536;   // PACKED
  // total ~202 MB

  hipMemsetAsync(d_ws, 0, zero_bytes, stream);

  // CSR build (deterministic per call)
  hist_kernel<<<2048, 256, 0, stream>>>(ei, deg);
  scan1_kernel<<<NBLK, 256, 0, stream>>>(deg, row, aux);
  scan2_kernel<<<1, 256, 0, stream>>>(aux);
  scan3_kernel<<<(NN + 255) / 256, 256, 0, stream>>>(row, aux);
  fill_kernel<<<2048, 256, 0, stream>>>(ei, row, cur, eidx);

  // convert inputs/weights to bf16 operand layouts
  conv_x<<<(NN * 32 + 255) / 256, 256, 0, stream>>>(x, A1);
  conv_w<<<112, 256, 0, stream>>>(W1l, W1r, W2l, W2r, Wf1, W1b, W2b, Wf1b);

  // pipeline (all GEMMs full-width, grid = 782 m-tiles)
  agg1_csr<<<25000, 256, 0, stream>>>(A1, row, eidx);
  gemm_kernel<256, 256, 16, 0, 0, 256, 0><<<MPAD / 128, 256, 0, stream>>>(
      A1, W1b, b1, nullptr, nullptr, A2, 512, 256, nullptr);
  agg2_csr<<<25000, 256, 0, stream>>>(A2, row, eidx);
  gemm_kernel<512, 512, 16, 0, 0, 256, 1><<<MPAD / 128, 256, 0, stream>>>(
      A2, W2b, b2, nullptr, nullptr, h2, 0, 0, nullptr);
  gemm_kernel<256, 256, 8, 1, 1, 128, 0><<<MPAD / 128, 256, 0, stream>>>(
      h2, Wf1b, bf1, Wf2, bf2, nullptr, 0, 0, out);
}

// Round 12
// 281.813 us; speedup vs baseline: 1.0465x; 1.0465x over previous
//
#include <hip/hip_runtime.h>
#include <hip/hip_bf16.h>

#define NN 100000
#define NE 600000
#define NBLK 98            // ceil(NN/1024) for the scan
#define MPAD 100096        // 782 * 128

typedef __attribute__((ext_vector_type(4))) int   i32x4;
typedef __attribute__((ext_vector_type(4))) float f32x4;

// ---------- helpers ----------
__device__ __forceinline__ float b2f(unsigned short u) {
  unsigned int v = ((unsigned int)u) << 16;
  return __uint_as_float(v);
}
__device__ __forceinline__ unsigned short f2b(float f) {
  __hip_bfloat16 h = __float2bfloat16(f);  // RNE
  return *reinterpret_cast<unsigned short*>(&h);
}
__device__ __forceinline__ float elu(float v) {
  return v > 0.0f ? v : (expf(v) - 1.0f);
}
__device__ __forceinline__ void gload_lds16(const void* g, void* l) {
  __builtin_amdgcn_global_load_lds(
      (const __attribute__((address_space(1))) void*)g,
      (__attribute__((address_space(3))) void*)l, 16, 0, 0);
}
__device__ __forceinline__ f32x4 mfma16(i32x4 a, i32x4 b, f32x4 c) {
  asm volatile("v_mfma_f32_16x16x32_bf16 %0, %1, %2, %0"
               : "+v"(c) : "v"(a), "v"(b));
  return c;
}

// packed fragment layouts (see R9): A-operand [ROWS x K]:
//   off(row,k) = (row/128)*(128*K) + (k/32)*4096 + ((row/16)%8)*512
//              + ((k/8)%4)*128 + (row%16)*8 + k%8
// B-operand [NC cols x K]:
//   off(col,k) = (k/32)*(NC*32) + (col/16)*512 + ((k/8)%4)*128 + (col%16)*8 + k%8

// ================= CSR build (by destination) =================
__global__ __launch_bounds__(256) void hist_kernel(
    const int* __restrict__ ei, int* __restrict__ deg) {
  const int* dst = ei + NE;
  int i = blockIdx.x * 256 + threadIdx.x;
  int n = gridDim.x * 256;
  for (int e = i; e < NE; e += n) atomicAdd(&deg[dst[e]], 1);
}

__global__ __launch_bounds__(256) void scan1_kernel(
    const int* __restrict__ deg, int* __restrict__ row, int* __restrict__ aux) {
  __shared__ int sd[256];
  int b = blockIdx.x, t = threadIdx.x;
  int base = b * 1024 + t * 4;
  int v0 = (base + 0 < NN) ? deg[base + 0] : 0;
  int v1 = (base + 1 < NN) ? deg[base + 1] : 0;
  int v2 = (base + 2 < NN) ? deg[base + 2] : 0;
  int v3 = (base + 3 < NN) ? deg[base + 3] : 0;
  int s = v0 + v1 + v2 + v3;
  sd[t] = s;
  __syncthreads();
  for (int off = 1; off < 256; off <<= 1) {
    int tmp = (t >= off) ? sd[t - off] : 0;
    __syncthreads();
    sd[t] += tmp;
    __syncthreads();
  }
  int excl = sd[t] - s;
  if (base + 0 < NN) row[base + 0] = excl;
  if (base + 1 < NN) row[base + 1] = excl + v0;
  if (base + 2 < NN) row[base + 2] = excl + v0 + v1;
  if (base + 3 < NN) row[base + 3] = excl + v0 + v1 + v2;
  if (t == 255) aux[b] = sd[t];
}

__global__ __launch_bounds__(256) void scan2_kernel(int* __restrict__ aux) {
  __shared__ int sd[256];
  int t = threadIdx.x;
  int v = (t < NBLK) ? aux[t] : 0;
  sd[t] = v;
  __syncthreads();
  for (int off = 1; off < 256; off <<= 1) {
    int tmp = (t >= off) ? sd[t - off] : 0;
    __syncthreads();
    sd[t] += tmp;
    __syncthreads();
  }
  if (t < NBLK) aux[t] = sd[t] - v;
}

__global__ __launch_bounds__(256) void scan3_kernel(
    int* __restrict__ row, const int* __restrict__ aux) {
  int i = blockIdx.x * 256 + threadIdx.x;
  if (i < NN) row[i] += aux[i >> 10];
  if (i == 0) row[NN] = NE;
}

__global__ __launch_bounds__(256) void fill_kernel(
    const int* __restrict__ ei, const int* __restrict__ row,
    int* __restrict__ cur, int* __restrict__ eidx) {
  const int* src = ei;
  const int* dst = ei + NE;
  int i = blockIdx.x * 256 + threadIdx.x;
  int n = gridDim.x * 256;
  for (int e = i; e < NE; e += n) {
    int d = dst[e];
    int p = atomicAdd(&cur[d], 1);
    eidx[row[d] + p] = src[e];
  }
}

// ============ conversions ============
__global__ __launch_bounds__(256) void conv_x(
    const float* __restrict__ x, unsigned short* __restrict__ A1) {
  int i = blockIdx.x * 256 + threadIdx.x;  // float4 groups
  if (i >= NN * 32) return;
  int n = i >> 5, k4 = i & 31;
  float4 v = ((const float4*)(x + (size_t)n * 128))[k4];
  ushort4 o;
  o.x = f2b(v.x); o.y = f2b(v.y); o.z = f2b(v.z); o.w = f2b(v.w);
  ((ushort4*)(A1 + (size_t)n * 256 + 128))[k4] = o;
}

// weights -> PACKED fragment layout (B-operand form).
__global__ __launch_bounds__(256) void conv_w(
    const float* __restrict__ W1l, const float* __restrict__ W1r,
    const float* __restrict__ W2l, const float* __restrict__ W2r,
    const float* __restrict__ Wf1,
    unsigned short* __restrict__ W1b, unsigned short* __restrict__ W2b,
    unsigned short* __restrict__ Wf1b) {
  int g = blockIdx.x * 256 + threadIdx.x;
  const float* src;
  unsigned short* dst;
  int j, k, NC;
  if (g < 8192) {                       // W1b: 256 cols x K=256 = [W1l|W1r]
    j = g >> 5; k = (g & 31) * 8; NC = 256; dst = W1b;
    src = (k < 128) ? (W1l + (size_t)j * 128 + k)
                    : (W1r + (size_t)j * 128 + (k - 128));
  } else if (g < 24576) {               // W2b: 256 cols x K=512 = [W2l|W2r]
    int h = g - 8192; j = h >> 6; k = (h & 63) * 8; NC = 256; dst = W2b;
    src = (k < 256) ? (W2l + (size_t)j * 256 + k)
                    : (W2r + (size_t)j * 256 + (k - 256));
  } else if (g < 28672) {               // Wf1b: 128 cols x K=256
    int h = g - 24576; j = h >> 5; k = (h & 31) * 8; NC = 128; dst = Wf1b;
    src = Wf1 + (size_t)j * 256 + k;
  } else return;
  float4 v0 = *(const float4*)src;
  float4 v1 = *(const float4*)(src + 4);
  unsigned short o[8] = {f2b(v0.x), f2b(v0.y), f2b(v0.z), f2b(v0.w),
                         f2b(v1.x), f2b(v1.y), f2b(v1.z), f2b(v1.w)};
  size_t off = (size_t)(k >> 5) * (NC * 32) + (j >> 4) * 512 +
               ((k >> 3) & 3) * 128 + (j & 15) * 8;
  *(i32x4*)(dst + off) = *(i32x4*)o;
}

// ============ aggregation via CSR gather, 16B/lane multi-edge ================
// agg1: 128-col rows (256B). 4 lane-groups of 16 gather 4 edges at once;
// each lane reads ushort8 (16B). Combine via shfl_xor(16,32); store 16B/lane
// from group 0 (256B coalesced).
__global__ __launch_bounds__(256) void agg1_csr(
    unsigned short* __restrict__ A1, const int* __restrict__ row,
    const int* __restrict__ eidx) {
  int lane = threadIdx.x & 63;
  int n = (blockIdx.x * 256 + threadIdx.x) >> 6;
  if (n >= NN) return;
  int r0 = row[n], r1 = row[n + 1];
  int g = lane >> 4, l16 = lane & 15;
  float acc[8] = {0, 0, 0, 0, 0, 0, 0, 0};
  int e = r0;
  for (; e + 3 < r1; e += 4) {
    int s = eidx[e + g];  // 4 distinct addrs, L1-hot
    i32x4 u = *(const i32x4*)(A1 + (size_t)s * 256 + 128 + l16 * 8);
    const unsigned short* p = (const unsigned short*)&u;
#pragma unroll
    for (int j = 0; j < 8; ++j) acc[j] += b2f(p[j]);
  }
  if (e + g < r1) {       // remainder 0..3 edges, group-predicated
    int s = eidx[e + g];
    i32x4 u = *(const i32x4*)(A1 + (size_t)s * 256 + 128 + l16 * 8);
    const unsigned short* p = (const unsigned short*)&u;
#pragma unroll
    for (int j = 0; j < 8; ++j) acc[j] += b2f(p[j]);
  }
  float inv = 1.0f / (float)max(r1 - r0, 1);
  unsigned short o[8];
#pragma unroll
  for (int j = 0; j < 8; ++j) {
    float v = acc[j] + __shfl_xor(acc[j], 16);
    v += __shfl_xor(v, 32);
    o[j] = f2b(v * inv);
  }
  if (g == 0) *(i32x4*)(A1 + (size_t)n * 256 + l16 * 8) = *(i32x4*)o;
}

// agg2: 256-col rows (512B). 2 lane-halves of 32 gather 2 edges at once;
// ushort8/lane. Combine via shfl_xor(32); store 16B/lane from half 0.
__global__ __launch_bounds__(256) void agg2_csr(
    unsigned short* __restrict__ A2, const int* __restrict__ row,
    const int* __restrict__ eidx) {
  int lane = threadIdx.x & 63;
  int n = (blockIdx.x * 256 + threadIdx.x) >> 6;
  if (n >= NN) return;
  int r0 = row[n], r1 = row[n + 1];
  int h = lane >> 5, l32 = lane & 31;
  float acc[8] = {0, 0, 0, 0, 0, 0, 0, 0};
  int e = r0;
  for (; e + 1 < r1; e += 2) {
    int s = eidx[e + h];
    i32x4 u = *(const i32x4*)(A2 + (size_t)s * 512 + 256 + l32 * 8);
    const unsigned short* p = (const unsigned short*)&u;
#pragma unroll
    for (int j = 0; j < 8; ++j) acc[j] += b2f(p[j]);
  }
  if (e + h < r1) {       // remainder edge handled by half 0 only
    int s = eidx[e + h];
    i32x4 u = *(const i32x4*)(A2 + (size_t)s * 512 + 256 + l32 * 8);
    const unsigned short* p = (const unsigned short*)&u;
#pragma unroll
    for (int j = 0; j < 8; ++j) acc[j] += b2f(p[j]);
  }
  float inv = 1.0f / (float)max(r1 - r0, 1);
  unsigned short o[8];
#pragma unroll
  for (int j = 0; j < 8; ++j) {
    float v = acc[j] + __shfl_xor(acc[j], 32);
    o[j] = f2b(v * inv);
  }
  if (h == 0) *(i32x4*)(A2 + (size_t)n * 512 + l32 * 8) = *(i32x4*)o;
}

// ============ MFMA GEMM: BM=128, BN=128, BK=32, 2-buf, race-hardened ==========
// R9 config verbatim (best measured): 4 blk/CU, packed B (+A for head), grid.y=2.
template <int K, int APITCH, int EPI, int AP, int BNC, int HPACK>
__global__ __launch_bounds__(256, 4) void gemm_kernel(
    const unsigned short* __restrict__ A, const unsigned short* __restrict__ Wb,
    const float* __restrict__ bias, const float* __restrict__ w2,
    const float* __restrict__ bf2p,
    unsigned short* __restrict__ Hout, int HPITCH, int HOFF,
    float* __restrict__ out) {
  __shared__ unsigned short lA[2][4096];
  __shared__ unsigned short lB[2][4096];
  int tid = threadIdx.x;
  int w = tid >> 6, lane = tid & 63;
  int lhi = lane >> 4, llo = lane & 15;
  int m0 = blockIdx.x * 128;
  int c0 = blockIdx.y * 128;
  int fb = lane * 8;  // fragment-local elem offset (16B/lane, bank-spread)

  f32x4 acc0[8], acc1[8];
#pragma unroll
  for (int n = 0; n < 8; ++n) { acc0[n] = (f32x4)0.f; acc1[n] = (f32x4)0.f; }

#define STAGE(t)                                                                \
  do {                                                                          \
    int _b = (t) & 1;                                                           \
    _Pragma("unroll")                                                           \
    for (int i = 0; i < 2; ++i) {                                               \
      int c = w * 2 + i;                                                        \
      const unsigned short* ga;                                                 \
      if constexpr (AP) {                                                       \
        ga = A + (size_t)(m0 >> 7) * (128 * K) + (size_t)(t) * 4096 +           \
             c * 512 + lane * 8;                                                \
      } else {                                                                  \
        ga = A + (size_t)(m0 + c * 16 + llo) * APITCH + (t) * 32 + lhi * 8;     \
      }                                                                         \
      gload_lds16(ga, &lA[_b][c * 512]);                                        \
      const unsigned short* gb = Wb + (size_t)(t) * (BNC * 32) +                \
                                 ((c0 >> 4) + c) * 512 + lane * 8;              \
      gload_lds16(gb, &lB[_b][c * 512]);                                        \
    }                                                                           \
  } while (0)

  constexpr int NSTEP = K / 32;
  STAGE(0);
  __builtin_amdgcn_sched_barrier(0);
  asm volatile("s_waitcnt vmcnt(0)" ::: "memory");
  __syncthreads();
  for (int t = 0; t < NSTEP; ++t) {
    if (t + 1 < NSTEP) STAGE(t + 1);
    const unsigned short* la = &lA[t & 1][0];
    const unsigned short* lb = &lB[t & 1][0];
    i32x4 a0 = *(const i32x4*)(la + (w * 2 + 0) * 512 + fb);
    i32x4 a1 = *(const i32x4*)(la + (w * 2 + 1) * 512 + fb);
#pragma unroll
    for (int n = 0; n < 8; ++n) {
      i32x4 b = *(const i32x4*)(lb + n * 512 + fb);
      acc0[n] = mfma16(a0, b, acc0[n]);
      acc1[n] = mfma16(a1, b, acc1[n]);
    }
    // pin all motion, then drain STAGE(t+1)'s DMA before the buffer handoff
    __builtin_amdgcn_sched_barrier(0);
    asm volatile("s_waitcnt vmcnt(0)" ::: "memory");
    __syncthreads();
  }
#undef STAGE
  asm volatile("s_nop 7\n\ts_nop 7");  // MFMA -> VALU read hazard

  if constexpr (EPI == 0) {
    float bv[8];
#pragma unroll
    for (int n = 0; n < 8; ++n) bv[n] = bias[c0 + n * 16 + llo];
#pragma unroll
    for (int mi = 0; mi < 2; ++mi) {
#pragma unroll
      for (int n = 0; n < 8; ++n) {
        f32x4 av = mi ? acc1[n] : acc0[n];
#pragma unroll
        for (int r = 0; r < 4; ++r) {
          int R = m0 + (w * 2 + mi) * 16 + lhi * 4 + r;
          float v = elu(av[r] + bv[n]);
          if constexpr (HPACK) {
            int col = c0 + n * 16 + llo;  // consumer K = 256
            size_t off = (size_t)(R >> 7) * 32768 + (col >> 5) * 4096 +
                         ((R >> 4) & 7) * 512 + ((col >> 3) & 3) * 128 +
                         (R & 15) * 8 + (col & 7);
            Hout[off] = f2b(v);
          } else {
            Hout[(size_t)R * HPITCH + HOFF + c0 + n * 16 + llo] = f2b(v);
          }
        }
      }
    }
  } else {
    float b1v[8], w2v[8];
#pragma unroll
    for (int n = 0; n < 8; ++n) {
      b1v[n] = bias[n * 16 + llo];
      w2v[n] = w2[n * 16 + llo];
    }
    float bf2v = bf2p[0];
#pragma unroll
    for (int mi = 0; mi < 2; ++mi) {
#pragma unroll
      for (int r = 0; r < 4; ++r) {
        float s = 0.f;
#pragma unroll
        for (int n = 0; n < 8; ++n) {
          f32x4 av = mi ? acc1[n] : acc0[n];
          s += fmaxf(av[r] + b1v[n], 0.f) * w2v[n];
        }
        s += __shfl_xor(s, 1);
        s += __shfl_xor(s, 2);
        s += __shfl_xor(s, 4);
        s += __shfl_xor(s, 8);
        int R = m0 + (w * 2 + mi) * 16 + lhi * 4 + r;
        if (llo == 0 && R < NN) out[R] = s + bf2v;
      }
    }
  }
}

extern "C" void kernel_launch(void* const* d_in, const int* in_sizes, int n_in,
                              void* d_out, int out_size, void* d_ws, size_t ws_size,
                              hipStream_t stream) {
  const float* x   = (const float*)d_in[0];
  const int*   ei  = (const int*)d_in[1];
  const float* W1l = (const float*)d_in[2];
  const float* b1  = (const float*)d_in[3];
  const float* W1r = (const float*)d_in[4];
  const float* W2l = (const float*)d_in[5];
  const float* b2  = (const float*)d_in[6];
  const float* W2r = (const float*)d_in[7];
  const float* Wf1 = (const float*)d_in[8];
  const float* bf1 = (const float*)d_in[9];
  const float* Wf2 = (const float*)d_in[10];
  const float* bf2 = (const float*)d_in[11];
  float* out = (float*)d_out;

  char* ws = (char*)d_ws;
  size_t o = 0;
  int* deg = (int*)(ws + o); o += 400384;   // zeroed each call
  int* cur = (int*)(ws + o); o += 400384;   // zeroed each call
  size_t zero_bytes = o;
  int* row  = (int*)(ws + o); o += 400640;  // NN+1
  int* aux  = (int*)(ws + o); o += 4096;
  int* eidx = (int*)(ws + o); o += 2400000;
  unsigned short* A1 = (unsigned short*)(ws + o); o += (size_t)MPAD * 256 * 2; // [mean1|x] row-major
  unsigned short* A2 = (unsigned short*)(ws + o); o += (size_t)MPAD * 512 * 2; // [mean2|h1] row-major
  unsigned short* h2 = (unsigned short*)(ws + o); o += (size_t)MPAD * 256 * 2; // PACKED
  unsigned short* W1b  = (unsigned short*)(ws + o); o += 131072;  // PACKED
  unsigned short* W2b  = (unsigned short*)(ws + o); o += 262144;  // PACKED
  unsigned short* Wf1b = (unsigned short*)(ws + o); o += 65536;   // PACKED
  // total ~202 MB

  hipMemsetAsync(d_ws, 0, zero_bytes, stream);

  // CSR build (deterministic per call)
  hist_kernel<<<2048, 256, 0, stream>>>(ei, deg);
  scan1_kernel<<<NBLK, 256, 0, stream>>>(deg, row, aux);
  scan2_kernel<<<1, 256, 0, stream>>>(aux);
  scan3_kernel<<<(NN + 255) / 256, 256, 0, stream>>>(row, aux);
  fill_kernel<<<2048, 256, 0, stream>>>(ei, row, cur, eidx);

  // convert inputs/weights to bf16 operand layouts
  conv_x<<<(NN * 32 + 255) / 256, 256, 0, stream>>>(x, A1);
  conv_w<<<112, 256, 0, stream>>>(W1l, W1r, W2l, W2r, Wf1, W1b, W2b, Wf1b);

  // pipeline (R9 GEMM config: NF=8, grid.y=2, 4 blk/CU)
  agg1_csr<<<25000, 256, 0, stream>>>(A1, row, eidx);
  gemm_kernel<256, 256, 0, 0, 256, 0><<<dim3(MPAD / 128, 2), 256, 0, stream>>>(
      A1, W1b, b1, nullptr, nullptr, A2, 512, 256, nullptr);
  agg2_csr<<<25000, 256, 0, stream>>>(A2, row, eidx);
  gemm_kernel<512, 512, 0, 0, 256, 1><<<dim3(MPAD / 128, 2), 256, 0, stream>>>(
      A2, W2b, b2, nullptr, nullptr, h2, 0, 0, nullptr);
  gemm_kernel<256, 256, 1, 1, 128, 0><<<dim3(MPAD / 128, 1), 256, 0, stream>>>(
      h2, Wf1b, bf1, Wf2, bf2, nullptr, 0, 0, out);
}

// Round 13
// 275.817 us; speedup vs baseline: 1.0693x; 1.0217x over previous
//
#include <hip/hip_runtime.h>
#include <hip/hip_bf16.h>

#define NN 100000
#define NE 600000
#define NBLK 98            // ceil(NN/1024) for the scan
#define MPAD 100096        // 782 * 128
#define NT   (MPAD / 128)  // 782 m-tiles

typedef __attribute__((ext_vector_type(4))) int   i32x4;
typedef __attribute__((ext_vector_type(4))) float f32x4;

// ---------- helpers ----------
__device__ __forceinline__ float b2f(unsigned short u) {
  unsigned int v = ((unsigned int)u) << 16;
  return __uint_as_float(v);
}
__device__ __forceinline__ unsigned short f2b(float f) {
  __hip_bfloat16 h = __float2bfloat16(f);  // RNE
  return *reinterpret_cast<unsigned short*>(&h);
}
__device__ __forceinline__ float elu(float v) {
  return v > 0.0f ? v : (expf(v) - 1.0f);
}
__device__ __forceinline__ void gload_lds16(const void* g, void* l) {
  __builtin_amdgcn_global_load_lds(
      (const __attribute__((address_space(1))) void*)g,
      (__attribute__((address_space(3))) void*)l, 16, 0, 0);
}
__device__ __forceinline__ f32x4 mfma16(i32x4 a, i32x4 b, f32x4 c) {
  asm volatile("v_mfma_f32_16x16x32_bf16 %0, %1, %2, %0"
               : "+v"(c) : "v"(a), "v"(b));
  return c;
}

// packed fragment layouts (see R9): A-operand [ROWS x K]:
//   off(row,k) = (row/128)*(128*K) + (k/32)*4096 + ((row/16)%8)*512
//              + ((k/8)%4)*128 + (row%16)*8 + k%8
// B-operand [NC cols x K]:
//   off(col,k) = (k/32)*(NC*32) + (col/16)*512 + ((k/8)%4)*128 + (col%16)*8 + k%8

// ================= CSR build (by destination) =================
__global__ __launch_bounds__(256) void hist_kernel(
    const int* __restrict__ ei, int* __restrict__ deg) {
  const int* dst = ei + NE;
  int i = blockIdx.x * 256 + threadIdx.x;
  int n = gridDim.x * 256;
  for (int e = i; e < NE; e += n) atomicAdd(&deg[dst[e]], 1);
}

__global__ __launch_bounds__(256) void scan1_kernel(
    const int* __restrict__ deg, int* __restrict__ row, int* __restrict__ aux) {
  __shared__ int sd[256];
  int b = blockIdx.x, t = threadIdx.x;
  int base = b * 1024 + t * 4;
  int v0 = (base + 0 < NN) ? deg[base + 0] : 0;
  int v1 = (base + 1 < NN) ? deg[base + 1] : 0;
  int v2 = (base + 2 < NN) ? deg[base + 2] : 0;
  int v3 = (base + 3 < NN) ? deg[base + 3] : 0;
  int s = v0 + v1 + v2 + v3;
  sd[t] = s;
  __syncthreads();
  for (int off = 1; off < 256; off <<= 1) {
    int tmp = (t >= off) ? sd[t - off] : 0;
    __syncthreads();
    sd[t] += tmp;
    __syncthreads();
  }
  int excl = sd[t] - s;
  if (base + 0 < NN) row[base + 0] = excl;
  if (base + 1 < NN) row[base + 1] = excl + v0;
  if (base + 2 < NN) row[base + 2] = excl + v0 + v1;
  if (base + 3 < NN) row[base + 3] = excl + v0 + v1 + v2;
  if (t == 255) aux[b] = sd[t];
}

__global__ __launch_bounds__(256) void scan2_kernel(int* __restrict__ aux) {
  __shared__ int sd[256];
  int t = threadIdx.x;
  int v = (t < NBLK) ? aux[t] : 0;
  sd[t] = v;
  __syncthreads();
  for (int off = 1; off < 256; off <<= 1) {
    int tmp = (t >= off) ? sd[t - off] : 0;
    __syncthreads();
    sd[t] += tmp;
    __syncthreads();
  }
  if (t < NBLK) aux[t] = sd[t] - v;
}

__global__ __launch_bounds__(256) void scan3_kernel(
    int* __restrict__ row, const int* __restrict__ aux) {
  int i = blockIdx.x * 256 + threadIdx.x;
  if (i < NN) row[i] += aux[i >> 10];
  if (i == 0) row[NN] = NE;
}

__global__ __launch_bounds__(256) void fill_kernel(
    const int* __restrict__ ei, const int* __restrict__ row,
    int* __restrict__ cur, int* __restrict__ eidx) {
  const int* src = ei;
  const int* dst = ei + NE;
  int i = blockIdx.x * 256 + threadIdx.x;
  int n = gridDim.x * 256;
  for (int e = i; e < NE; e += n) {
    int d = dst[e];
    int p = atomicAdd(&cur[d], 1);
    eidx[row[d] + p] = src[e];
  }
}

// ============ conversions ============
__global__ __launch_bounds__(256) void conv_x(
    const float* __restrict__ x, unsigned short* __restrict__ A1) {
  int i = blockIdx.x * 256 + threadIdx.x;  // float4 groups
  if (i >= NN * 32) return;
  int n = i >> 5, k4 = i & 31;
  float4 v = ((const float4*)(x + (size_t)n * 128))[k4];
  ushort4 o;
  o.x = f2b(v.x); o.y = f2b(v.y); o.z = f2b(v.z); o.w = f2b(v.w);
  ((ushort4*)(A1 + (size_t)n * 256 + 128))[k4] = o;
}

// weights -> PACKED fragment layout (B-operand form).
__global__ __launch_bounds__(256) void conv_w(
    const float* __restrict__ W1l, const float* __restrict__ W1r,
    const float* __restrict__ W2l, const float* __restrict__ W2r,
    const float* __restrict__ Wf1,
    unsigned short* __restrict__ W1b, unsigned short* __restrict__ W2b,
    unsigned short* __restrict__ Wf1b) {
  int g = blockIdx.x * 256 + threadIdx.x;
  const float* src;
  unsigned short* dst;
  int j, k, NC;
  if (g < 8192) {                       // W1b: 256 cols x K=256 = [W1l|W1r]
    j = g >> 5; k = (g & 31) * 8; NC = 256; dst = W1b;
    src = (k < 128) ? (W1l + (size_t)j * 128 + k)
                    : (W1r + (size_t)j * 128 + (k - 128));
  } else if (g < 24576) {               // W2b: 256 cols x K=512 = [W2l|W2r]
    int h = g - 8192; j = h >> 6; k = (h & 63) * 8; NC = 256; dst = W2b;
    src = (k < 256) ? (W2l + (size_t)j * 256 + k)
                    : (W2r + (size_t)j * 256 + (k - 256));
  } else if (g < 28672) {               // Wf1b: 128 cols x K=256
    int h = g - 24576; j = h >> 5; k = (h & 31) * 8; NC = 128; dst = Wf1b;
    src = Wf1 + (size_t)j * 256 + k;
  } else return;
  float4 v0 = *(const float4*)src;
  float4 v1 = *(const float4*)(src + 4);
  unsigned short o[8] = {f2b(v0.x), f2b(v0.y), f2b(v0.z), f2b(v0.w),
                         f2b(v1.x), f2b(v1.y), f2b(v1.z), f2b(v1.w)};
  size_t off = (size_t)(k >> 5) * (NC * 32) + (j >> 4) * 512 +
               ((k >> 3) & 3) * 128 + (j & 15) * 8;
  *(i32x4*)(dst + off) = *(i32x4*)o;
}

// ============ aggregation via CSR gather, 16B/lane multi-edge ================
__global__ __launch_bounds__(256) void agg1_csr(
    unsigned short* __restrict__ A1, const int* __restrict__ row,
    const int* __restrict__ eidx) {
  int lane = threadIdx.x & 63;
  int n = (blockIdx.x * 256 + threadIdx.x) >> 6;
  if (n >= NN) return;
  int r0 = row[n], r1 = row[n + 1];
  int g = lane >> 4, l16 = lane & 15;
  float acc[8] = {0, 0, 0, 0, 0, 0, 0, 0};
  int e = r0;
  for (; e + 3 < r1; e += 4) {
    int s = eidx[e + g];  // 4 distinct addrs, L1-hot
    i32x4 u = *(const i32x4*)(A1 + (size_t)s * 256 + 128 + l16 * 8);
    const unsigned short* p = (const unsigned short*)&u;
#pragma unroll
    for (int j = 0; j < 8; ++j) acc[j] += b2f(p[j]);
  }
  if (e + g < r1) {       // remainder 0..3 edges, group-predicated
    int s = eidx[e + g];
    i32x4 u = *(const i32x4*)(A1 + (size_t)s * 256 + 128 + l16 * 8);
    const unsigned short* p = (const unsigned short*)&u;
#pragma unroll
    for (int j = 0; j < 8; ++j) acc[j] += b2f(p[j]);
  }
  float inv = 1.0f / (float)max(r1 - r0, 1);
  unsigned short o[8];
#pragma unroll
  for (int j = 0; j < 8; ++j) {
    float v = acc[j] + __shfl_xor(acc[j], 16);
    v += __shfl_xor(v, 32);
    o[j] = f2b(v * inv);
  }
  if (g == 0) *(i32x4*)(A1 + (size_t)n * 256 + l16 * 8) = *(i32x4*)o;
}

__global__ __launch_bounds__(256) void agg2_csr(
    unsigned short* __restrict__ A2, const int* __restrict__ row,
    const int* __restrict__ eidx) {
  int lane = threadIdx.x & 63;
  int n = (blockIdx.x * 256 + threadIdx.x) >> 6;
  if (n >= NN) return;
  int r0 = row[n], r1 = row[n + 1];
  int h = lane >> 5, l32 = lane & 31;
  float acc[8] = {0, 0, 0, 0, 0, 0, 0, 0};
  int e = r0;
  for (; e + 1 < r1; e += 2) {
    int s = eidx[e + h];
    i32x4 u = *(const i32x4*)(A2 + (size_t)s * 512 + 256 + l32 * 8);
    const unsigned short* p = (const unsigned short*)&u;
#pragma unroll
    for (int j = 0; j < 8; ++j) acc[j] += b2f(p[j]);
  }
  if (e + h < r1) {       // remainder edge handled by half 0 only
    int s = eidx[e + h];
    i32x4 u = *(const i32x4*)(A2 + (size_t)s * 512 + 256 + l32 * 8);
    const unsigned short* p = (const unsigned short*)&u;
#pragma unroll
    for (int j = 0; j < 8; ++j) acc[j] += b2f(p[j]);
  }
  float inv = 1.0f / (float)max(r1 - r0, 1);
  unsigned short o[8];
#pragma unroll
  for (int j = 0; j < 8; ++j) {
    float v = acc[j] + __shfl_xor(acc[j], 32);
    o[j] = f2b(v * inv);
  }
  if (h == 0) *(i32x4*)(A2 + (size_t)n * 512 + l32 * 8) = *(i32x4*)o;
}

// ============ MFMA GEMM: BM=128, BN=128, BK=32, 2-buf, race-hardened ==========
// R9 structure; now 5 blk/CU (LDS 5x32KB = 160KB exactly; VGPR 48 << 102 cap)
// and, for GY=2, a 1D grid with XCD-PAIR swizzle: both column-blocks of one
// m-tile get workgroup ids congruent mod 8 -> same XCD -> 2nd A-stage is L2-hot.
//   wgid < G16: m = (wgid>>4)*8 + (wgid&7), cb = (wgid>>3)&1   [G16 = (NT/8)*16]
//   tail:       t = wgid-G16; m = (NT/8)*8 + t%TAIL, cb = t/TAIL [TAIL = NT%8]
template <int K, int APITCH, int EPI, int AP, int BNC, int HPACK, int GY>
__global__ __launch_bounds__(256, 5) void gemm_kernel(
    const unsigned short* __restrict__ A, const unsigned short* __restrict__ Wb,
    const float* __restrict__ bias, const float* __restrict__ w2,
    const float* __restrict__ bf2p,
    unsigned short* __restrict__ Hout, int HPITCH, int HOFF,
    float* __restrict__ out) {
  __shared__ unsigned short lA[2][4096];
  __shared__ unsigned short lB[2][4096];
  int tid = threadIdx.x;
  int w = tid >> 6, lane = tid & 63;
  int lhi = lane >> 4, llo = lane & 15;

  int m0, c0;
  if constexpr (GY == 2) {
    constexpr int G16 = (NT / 8) * 16;   // 1552
    constexpr int TAIL = NT % 8;         // 6
    int wgid = blockIdx.x;
    int m, cb;
    if (wgid < G16) {
      m = (wgid >> 4) * 8 + (wgid & 7);
      cb = (wgid >> 3) & 1;
    } else {
      int t = wgid - G16;
      m = (NT / 8) * 8 + t % TAIL;
      cb = t / TAIL;
    }
    m0 = m * 128;
    c0 = cb * 128;
  } else {
    m0 = blockIdx.x * 128;
    c0 = 0;
  }
  int fb = lane * 8;  // fragment-local elem offset (16B/lane, bank-spread)

  f32x4 acc0[8], acc1[8];
#pragma unroll
  for (int n = 0; n < 8; ++n) { acc0[n] = (f32x4)0.f; acc1[n] = (f32x4)0.f; }

#define STAGE(t)                                                                \
  do {                                                                          \
    int _b = (t) & 1;                                                           \
    _Pragma("unroll")                                                           \
    for (int i = 0; i < 2; ++i) {                                               \
      int c = w * 2 + i;                                                        \
      const unsigned short* ga;                                                 \
      if constexpr (AP) {                                                       \
        ga = A + (size_t)(m0 >> 7) * (128 * K) + (size_t)(t) * 4096 +           \
             c * 512 + lane * 8;                                                \
      } else {                                                                  \
        ga = A + (size_t)(m0 + c * 16 + llo) * APITCH + (t) * 32 + lhi * 8;     \
      }                                                                         \
      gload_lds16(ga, &lA[_b][c * 512]);                                        \
      const unsigned short* gb = Wb + (size_t)(t) * (BNC * 32) +                \
                                 ((c0 >> 4) + c) * 512 + lane * 8;              \
      gload_lds16(gb, &lB[_b][c * 512]);                                        \
    }                                                                           \
  } while (0)

  constexpr int NSTEP = K / 32;
  STAGE(0);
  __builtin_amdgcn_sched_barrier(0);
  asm volatile("s_waitcnt vmcnt(0)" ::: "memory");
  __syncthreads();
  for (int t = 0; t < NSTEP; ++t) {
    if (t + 1 < NSTEP) STAGE(t + 1);
    const unsigned short* la = &lA[t & 1][0];
    const unsigned short* lb = &lB[t & 1][0];
    i32x4 a0 = *(const i32x4*)(la + (w * 2 + 0) * 512 + fb);
    i32x4 a1 = *(const i32x4*)(la + (w * 2 + 1) * 512 + fb);
#pragma unroll
    for (int n = 0; n < 8; ++n) {
      i32x4 b = *(const i32x4*)(lb + n * 512 + fb);
      acc0[n] = mfma16(a0, b, acc0[n]);
      acc1[n] = mfma16(a1, b, acc1[n]);
    }
    // pin all motion, then drain STAGE(t+1)'s DMA before the buffer handoff
    __builtin_amdgcn_sched_barrier(0);
    asm volatile("s_waitcnt vmcnt(0)" ::: "memory");
    __syncthreads();
  }
#undef STAGE
  asm volatile("s_nop 7\n\ts_nop 7");  // MFMA -> VALU read hazard

  if constexpr (EPI == 0) {
    float bv[8];
#pragma unroll
    for (int n = 0; n < 8; ++n) bv[n] = bias[c0 + n * 16 + llo];
#pragma unroll
    for (int mi = 0; mi < 2; ++mi) {
#pragma unroll
      for (int n = 0; n < 8; ++n) {
        f32x4 av = mi ? acc1[n] : acc0[n];
#pragma unroll
        for (int r = 0; r < 4; ++r) {
          int R = m0 + (w * 2 + mi) * 16 + lhi * 4 + r;
          float v = elu(av[r] + bv[n]);
          if constexpr (HPACK) {
            int col = c0 + n * 16 + llo;  // consumer K = 256
            size_t off = (size_t)(R >> 7) * 32768 + (col >> 5) * 4096 +
                         ((R >> 4) & 7) * 512 + ((col >> 3) & 3) * 128 +
                         (R & 15) * 8 + (col & 7);
            Hout[off] = f2b(v);
          } else {
            Hout[(size_t)R * HPITCH + HOFF + c0 + n * 16 + llo] = f2b(v);
          }
        }
      }
    }
  } else {
    float b1v[8], w2v[8];
#pragma unroll
    for (int n = 0; n < 8; ++n) {
      b1v[n] = bias[n * 16 + llo];
      w2v[n] = w2[n * 16 + llo];
    }
    float bf2v = bf2p[0];
#pragma unroll
    for (int mi = 0; mi < 2; ++mi) {
#pragma unroll
      for (int r = 0; r < 4; ++r) {
        float s = 0.f;
#pragma unroll
        for (int n = 0; n < 8; ++n) {
          f32x4 av = mi ? acc1[n] : acc0[n];
          s += fmaxf(av[r] + b1v[n], 0.f) * w2v[n];
        }
        s += __shfl_xor(s, 1);
        s += __shfl_xor(s, 2);
        s += __shfl_xor(s, 4);
        s += __shfl_xor(s, 8);
        int R = m0 + (w * 2 + mi) * 16 + lhi * 4 + r;
        if (llo == 0 && R < NN) out[R] = s + bf2v;
      }
    }
  }
}

extern "C" void kernel_launch(void* const* d_in, const int* in_sizes, int n_in,
                              void* d_out, int out_size, void* d_ws, size_t ws_size,
                              hipStream_t stream) {
  const float* x   = (const float*)d_in[0];
  const int*   ei  = (const int*)d_in[1];
  const float* W1l = (const float*)d_in[2];
  const float* b1  = (const float*)d_in[3];
  const float* W1r = (const float*)d_in[4];
  const float* W2l = (const float*)d_in[5];
  const float* b2  = (const float*)d_in[6];
  const float* W2r = (const float*)d_in[7];
  const float* Wf1 = (const float*)d_in[8];
  const float* bf1 = (const float*)d_in[9];
  const float* Wf2 = (const float*)d_in[10];
  const float* bf2 = (const float*)d_in[11];
  float* out = (float*)d_out;

  char* ws = (char*)d_ws;
  size_t o = 0;
  int* deg = (int*)(ws + o); o += 400384;   // zeroed each call
  int* cur = (int*)(ws + o); o += 400384;   // zeroed each call
  size_t zero_bytes = o;
  int* row  = (int*)(ws + o); o += 400640;  // NN+1
  int* aux  = (int*)(ws + o); o += 4096;
  int* eidx = (int*)(ws + o); o += 2400000;
  unsigned short* A1 = (unsigned short*)(ws + o); o += (size_t)MPAD * 256 * 2; // [mean1|x] row-major
  unsigned short* A2 = (unsigned short*)(ws + o); o += (size_t)MPAD * 512 * 2; // [mean2|h1] row-major
  unsigned short* h2 = (unsigned short*)(ws + o); o += (size_t)MPAD * 256 * 2; // PACKED
  unsigned short* W1b  = (unsigned short*)(ws + o); o += 131072;  // PACKED
  unsigned short* W2b  = (unsigned short*)(ws + o); o += 262144;  // PACKED
  unsigned short* Wf1b = (unsigned short*)(ws + o); o += 65536;   // PACKED
  // total ~202 MB

  hipMemsetAsync(d_ws, 0, zero_bytes, stream);

  // CSR build (deterministic per call)
  hist_kernel<<<2048, 256, 0, stream>>>(ei, deg);
  scan1_kernel<<<NBLK, 256, 0, stream>>>(deg, row, aux);
  scan2_kernel<<<1, 256, 0, stream>>>(aux);
  scan3_kernel<<<(NN + 255) / 256, 256, 0, stream>>>(row, aux);
  fill_kernel<<<2048, 256, 0, stream>>>(ei, row, cur, eidx);

  // convert inputs/weights to bf16 operand layouts
  conv_x<<<(NN * 32 + 255) / 256, 256, 0, stream>>>(x, A1);
  conv_w<<<112, 256, 0, stream>>>(W1l, W1r, W2l, W2r, Wf1, W1b, W2b, Wf1b);

  // pipeline (1D grids; GY=2 GEMMs use the XCD-pair swizzle internally)
  agg1_csr<<<25000, 256, 0, stream>>>(A1, row, eidx);
  gemm_kernel<256, 256, 0, 0, 256, 0, 2><<<NT * 2, 256, 0, stream>>>(
      A1, W1b, b1, nullptr, nullptr, A2, 512, 256, nullptr);
  agg2_csr<<<25000, 256, 0, stream>>>(A2, row, eidx);
  gemm_kernel<512, 512, 0, 0, 256, 1, 2><<<NT * 2, 256, 0, stream>>>(
      A2, W2b, b2, nullptr, nullptr, h2, 0, 0, nullptr);
  gemm_kernel<256, 256, 1, 1, 128, 0, 1><<<NT, 256, 0, stream>>>(
      h2, Wf1b, bf1, Wf2, bf2, nullptr, 0, 0, out);
}

// Round 14
// 271.481 us; speedup vs baseline: 1.0864x; 1.0160x over previous
//
#include <hip/hip_runtime.h>
#include <hip/hip_bf16.h>

#define NN 100000
#define NE 600000
#define NBLK 98            // ceil(NN/1024) for the scan
#define MPAD 100096        // 782 * 128
#define NT   (MPAD / 128)  // 782 m-tiles

typedef __attribute__((ext_vector_type(4))) int   i32x4;
typedef __attribute__((ext_vector_type(4))) float f32x4;

// ---------- helpers ----------
__device__ __forceinline__ float b2f(unsigned short u) {
  unsigned int v = ((unsigned int)u) << 16;
  return __uint_as_float(v);
}
__device__ __forceinline__ unsigned short f2b(float f) {
  __hip_bfloat16 h = __float2bfloat16(f);  // RNE
  return *reinterpret_cast<unsigned short*>(&h);
}
__device__ __forceinline__ float elu(float v) {
  return v > 0.0f ? v : (expf(v) - 1.0f);
}
__device__ __forceinline__ void gload_lds16(const void* g, void* l) {
  __builtin_amdgcn_global_load_lds(
      (const __attribute__((address_space(1))) void*)g,
      (__attribute__((address_space(3))) void*)l, 16, 0, 0);
}
__device__ __forceinline__ f32x4 mfma16(i32x4 a, i32x4 b, f32x4 c) {
  asm volatile("v_mfma_f32_16x16x32_bf16 %0, %1, %2, %0"
               : "+v"(c) : "v"(a), "v"(b));
  return c;
}

// packed fragment layouts (see R9): A-operand [ROWS x K]:
//   off(row,k) = (row/128)*(128*K) + (k/32)*4096 + ((row/16)%8)*512
//              + ((k/8)%4)*128 + (row%16)*8 + k%8
// B-operand [NC cols x K]:
//   off(col,k) = (k/32)*(NC*32) + (col/16)*512 + ((k/8)%4)*128 + (col%16)*8 + k%8

// ================= CSR build (by destination) =================
__global__ __launch_bounds__(256) void hist_kernel(
    const int* __restrict__ ei, int* __restrict__ deg) {
  const int* dst = ei + NE;
  int i = blockIdx.x * 256 + threadIdx.x;
  int n = gridDim.x * 256;
  for (int e = i; e < NE; e += n) atomicAdd(&deg[dst[e]], 1);
}

__global__ __launch_bounds__(256) void scan1_kernel(
    const int* __restrict__ deg, int* __restrict__ row, int* __restrict__ aux) {
  __shared__ int sd[256];
  int b = blockIdx.x, t = threadIdx.x;
  int base = b * 1024 + t * 4;
  int v0 = (base + 0 < NN) ? deg[base + 0] : 0;
  int v1 = (base + 1 < NN) ? deg[base + 1] : 0;
  int v2 = (base + 2 < NN) ? deg[base + 2] : 0;
  int v3 = (base + 3 < NN) ? deg[base + 3] : 0;
  int s = v0 + v1 + v2 + v3;
  sd[t] = s;
  __syncthreads();
  for (int off = 1; off < 256; off <<= 1) {
    int tmp = (t >= off) ? sd[t - off] : 0;
    __syncthreads();
    sd[t] += tmp;
    __syncthreads();
  }
  int excl = sd[t] - s;
  if (base + 0 < NN) row[base + 0] = excl;
  if (base + 1 < NN) row[base + 1] = excl + v0;
  if (base + 2 < NN) row[base + 2] = excl + v0 + v1;
  if (base + 3 < NN) row[base + 3] = excl + v0 + v1 + v2;
  if (t == 255) aux[b] = sd[t];
}

__global__ __launch_bounds__(256) void scan2_kernel(int* __restrict__ aux) {
  __shared__ int sd[256];
  int t = threadIdx.x;
  int v = (t < NBLK) ? aux[t] : 0;
  sd[t] = v;
  __syncthreads();
  for (int off = 1; off < 256; off <<= 1) {
    int tmp = (t >= off) ? sd[t - off] : 0;
    __syncthreads();
    sd[t] += tmp;
    __syncthreads();
  }
  if (t < NBLK) aux[t] = sd[t] - v;
}

__global__ __launch_bounds__(256) void scan3_kernel(
    int* __restrict__ row, const int* __restrict__ aux) {
  int i = blockIdx.x * 256 + threadIdx.x;
  if (i < NN) row[i] += aux[i >> 10];
  if (i == 0) row[NN] = NE;
}

__global__ __launch_bounds__(256) void fill_kernel(
    const int* __restrict__ ei, const int* __restrict__ row,
    int* __restrict__ cur, int* __restrict__ eidx) {
  const int* src = ei;
  const int* dst = ei + NE;
  int i = blockIdx.x * 256 + threadIdx.x;
  int n = gridDim.x * 256;
  for (int e = i; e < NE; e += n) {
    int d = dst[e];
    int p = atomicAdd(&cur[d], 1);
    eidx[row[d] + p] = src[e];
  }
}

// ============ conversions ============
__global__ __launch_bounds__(256) void conv_x(
    const float* __restrict__ x, unsigned short* __restrict__ A1) {
  int i = blockIdx.x * 256 + threadIdx.x;  // float4 groups
  if (i >= NN * 32) return;
  int n = i >> 5, k4 = i & 31;
  float4 v = ((const float4*)(x + (size_t)n * 128))[k4];
  ushort4 o;
  o.x = f2b(v.x); o.y = f2b(v.y); o.z = f2b(v.z); o.w = f2b(v.w);
  ((ushort4*)(A1 + (size_t)n * 256 + 128))[k4] = o;
}

// weights -> PACKED fragment layout (B-operand form).
__global__ __launch_bounds__(256) void conv_w(
    const float* __restrict__ W1l, const float* __restrict__ W1r,
    const float* __restrict__ W2l, const float* __restrict__ W2r,
    const float* __restrict__ Wf1,
    unsigned short* __restrict__ W1b, unsigned short* __restrict__ W2b,
    unsigned short* __restrict__ Wf1b) {
  int g = blockIdx.x * 256 + threadIdx.x;
  const float* src;
  unsigned short* dst;
  int j, k, NC;
  if (g < 8192) {                       // W1b: 256 cols x K=256 = [W1l|W1r]
    j = g >> 5; k = (g & 31) * 8; NC = 256; dst = W1b;
    src = (k < 128) ? (W1l + (size_t)j * 128 + k)
                    : (W1r + (size_t)j * 128 + (k - 128));
  } else if (g < 24576) {               // W2b: 256 cols x K=512 = [W2l|W2r]
    int h = g - 8192; j = h >> 6; k = (h & 63) * 8; NC = 256; dst = W2b;
    src = (k < 256) ? (W2l + (size_t)j * 256 + k)
                    : (W2r + (size_t)j * 256 + (k - 256));
  } else if (g < 28672) {               // Wf1b: 128 cols x K=256
    int h = g - 24576; j = h >> 5; k = (h & 31) * 8; NC = 128; dst = Wf1b;
    src = Wf1 + (size_t)j * 256 + k;
  } else return;
  float4 v0 = *(const float4*)src;
  float4 v1 = *(const float4*)(src + 4);
  unsigned short o[8] = {f2b(v0.x), f2b(v0.y), f2b(v0.z), f2b(v0.w),
                         f2b(v1.x), f2b(v1.y), f2b(v1.z), f2b(v1.w)};
  size_t off = (size_t)(k >> 5) * (NC * 32) + (j >> 4) * 512 +
               ((k >> 3) & 3) * 128 + (j & 15) * 8;
  *(i32x4*)(dst + off) = *(i32x4*)o;
}

// ============ aggregation via CSR gather, 16B/lane multi-edge ================
__global__ __launch_bounds__(256) void agg1_csr(
    unsigned short* __restrict__ A1, const int* __restrict__ row,
    const int* __restrict__ eidx) {
  int lane = threadIdx.x & 63;
  int n = (blockIdx.x * 256 + threadIdx.x) >> 6;
  if (n >= NN) return;
  int r0 = row[n], r1 = row[n + 1];
  int g = lane >> 4, l16 = lane & 15;
  float acc[8] = {0, 0, 0, 0, 0, 0, 0, 0};
  int e = r0;
  for (; e + 3 < r1; e += 4) {
    int s = eidx[e + g];  // 4 distinct addrs, L1-hot
    i32x4 u = *(const i32x4*)(A1 + (size_t)s * 256 + 128 + l16 * 8);
    const unsigned short* p = (const unsigned short*)&u;
#pragma unroll
    for (int j = 0; j < 8; ++j) acc[j] += b2f(p[j]);
  }
  if (e + g < r1) {       // remainder 0..3 edges, group-predicated
    int s = eidx[e + g];
    i32x4 u = *(const i32x4*)(A1 + (size_t)s * 256 + 128 + l16 * 8);
    const unsigned short* p = (const unsigned short*)&u;
#pragma unroll
    for (int j = 0; j < 8; ++j) acc[j] += b2f(p[j]);
  }
  float inv = 1.0f / (float)max(r1 - r0, 1);
  unsigned short o[8];
#pragma unroll
  for (int j = 0; j < 8; ++j) {
    float v = acc[j] + __shfl_xor(acc[j], 16);
    v += __shfl_xor(v, 32);
    o[j] = f2b(v * inv);
  }
  if (g == 0) *(i32x4*)(A1 + (size_t)n * 256 + l16 * 8) = *(i32x4*)o;
}

__global__ __launch_bounds__(256) void agg2_csr(
    unsigned short* __restrict__ A2, const int* __restrict__ row,
    const int* __restrict__ eidx) {
  int lane = threadIdx.x & 63;
  int n = (blockIdx.x * 256 + threadIdx.x) >> 6;
  if (n >= NN) return;
  int r0 = row[n], r1 = row[n + 1];
  int h = lane >> 5, l32 = lane & 31;
  float acc[8] = {0, 0, 0, 0, 0, 0, 0, 0};
  int e = r0;
  for (; e + 1 < r1; e += 2) {
    int s = eidx[e + h];
    i32x4 u = *(const i32x4*)(A2 + (size_t)s * 512 + 256 + l32 * 8);
    const unsigned short* p = (const unsigned short*)&u;
#pragma unroll
    for (int j = 0; j < 8; ++j) acc[j] += b2f(p[j]);
  }
  if (e + h < r1) {       // remainder edge handled by half 0 only
    int s = eidx[e + h];
    i32x4 u = *(const i32x4*)(A2 + (size_t)s * 512 + 256 + l32 * 8);
    const unsigned short* p = (const unsigned short*)&u;
#pragma unroll
    for (int j = 0; j < 8; ++j) acc[j] += b2f(p[j]);
  }
  float inv = 1.0f / (float)max(r1 - r0, 1);
  unsigned short o[8];
#pragma unroll
  for (int j = 0; j < 8; ++j) {
    float v = acc[j] + __shfl_xor(acc[j], 32);
    o[j] = f2b(v * inv);
  }
  if (h == 0) *(i32x4*)(A2 + (size_t)n * 512 + l32 * 8) = *(i32x4*)o;
}

// ===== MFMA GEMM: BM=128, BN=128, BK=32, 2-buf, COUNTED-vmcnt (T4) ===========
// R12 structure (5 blk/CU, packed B/h2, XCD-pair swizzle) with the drain-free
// schedule: per iter, wait vmcnt(4) = own STAGE(t) landed (issued a full step
// ago -> ~zero wait), raw s_barrier (NOT __syncthreads -- that drains vmcnt!),
// compute(t), barrier, STAGE(t+2) into buf t&1 (safe: all waves' ds_reads of
// buf t&1 were consumed by MFMAs before that barrier).
template <int K, int APITCH, int EPI, int AP, int BNC, int HPACK, int GY>
__global__ __launch_bounds__(256, 5) void gemm_kernel(
    const unsigned short* __restrict__ A, const unsigned short* __restrict__ Wb,
    const float* __restrict__ bias, const float* __restrict__ w2,
    const float* __restrict__ bf2p,
    unsigned short* __restrict__ Hout, int HPITCH, int HOFF,
    float* __restrict__ out) {
  __shared__ unsigned short lA[2][4096];
  __shared__ unsigned short lB[2][4096];
  int tid = threadIdx.x;
  int w = tid >> 6, lane = tid & 63;
  int lhi = lane >> 4, llo = lane & 15;

  int m0, c0;
  if constexpr (GY == 2) {
    constexpr int G16 = (NT / 8) * 16;   // 1552
    constexpr int TAIL = NT % 8;         // 6
    int wgid = blockIdx.x;
    int m, cb;
    if (wgid < G16) {
      m = (wgid >> 4) * 8 + (wgid & 7);
      cb = (wgid >> 3) & 1;
    } else {
      int t = wgid - G16;
      m = (NT / 8) * 8 + t % TAIL;
      cb = t / TAIL;
    }
    m0 = m * 128;
    c0 = cb * 128;
  } else {
    m0 = blockIdx.x * 128;
    c0 = 0;
  }
  int fb = lane * 8;  // fragment-local elem offset (16B/lane, bank-spread)

  f32x4 acc0[8], acc1[8];
#pragma unroll
  for (int n = 0; n < 8; ++n) { acc0[n] = (f32x4)0.f; acc1[n] = (f32x4)0.f; }

#define STAGE(t)                                                                \
  do {                                                                          \
    int _b = (t) & 1;                                                           \
    _Pragma("unroll")                                                           \
    for (int i = 0; i < 2; ++i) {                                               \
      int c = w * 2 + i;                                                        \
      const unsigned short* ga;                                                 \
      if constexpr (AP) {                                                       \
        ga = A + (size_t)(m0 >> 7) * (128 * K) + (size_t)(t) * 4096 +           \
             c * 512 + lane * 8;                                                \
      } else {                                                                  \
        ga = A + (size_t)(m0 + c * 16 + llo) * APITCH + (t) * 32 + lhi * 8;     \
      }                                                                         \
      gload_lds16(ga, &lA[_b][c * 512]);                                        \
      const unsigned short* gb = Wb + (size_t)(t) * (BNC * 32) +                \
                                 ((c0 >> 4) + c) * 512 + lane * 8;              \
      gload_lds16(gb, &lB[_b][c * 512]);                                        \
    }                                                                           \
  } while (0)

  constexpr int NSTEP = K / 32;
  STAGE(0);
  STAGE(1);
  __builtin_amdgcn_sched_barrier(0);
#pragma unroll
  for (int t = 0; t < NSTEP; ++t) {
    // wait for own STAGE(t) only (4 newer loads from STAGE(t+1) may remain)
    if (t + 1 < NSTEP) {
      asm volatile("s_waitcnt vmcnt(4)" ::: "memory");
    } else {
      asm volatile("s_waitcnt vmcnt(0)" ::: "memory");
    }
    __builtin_amdgcn_s_barrier();        // all waves' STAGE(t) landed
    __builtin_amdgcn_sched_barrier(0);
    const unsigned short* la = &lA[t & 1][0];
    const unsigned short* lb = &lB[t & 1][0];
    i32x4 a0 = *(const i32x4*)(la + (w * 2 + 0) * 512 + fb);
    i32x4 a1 = *(const i32x4*)(la + (w * 2 + 1) * 512 + fb);
#pragma unroll
    for (int n = 0; n < 8; ++n) {
      i32x4 b = *(const i32x4*)(lb + n * 512 + fb);
      acc0[n] = mfma16(a0, b, acc0[n]);
      acc1[n] = mfma16(a1, b, acc1[n]);
    }
    __builtin_amdgcn_sched_barrier(0);
    if (t + 2 < NSTEP) {
      __builtin_amdgcn_s_barrier();      // all reads of buf t&1 complete
      STAGE(t + 2);                      // overwrites buf t&1
      __builtin_amdgcn_sched_barrier(0);
    }
  }
#undef STAGE
  asm volatile("s_nop 7\n\ts_nop 7");  // MFMA -> VALU read hazard

  if constexpr (EPI == 0) {
    float bv[8];
#pragma unroll
    for (int n = 0; n < 8; ++n) bv[n] = bias[c0 + n * 16 + llo];
#pragma unroll
    for (int mi = 0; mi < 2; ++mi) {
#pragma unroll
      for (int n = 0; n < 8; ++n) {
        f32x4 av = mi ? acc1[n] : acc0[n];
#pragma unroll
        for (int r = 0; r < 4; ++r) {
          int R = m0 + (w * 2 + mi) * 16 + lhi * 4 + r;
          float v = elu(av[r] + bv[n]);
          if constexpr (HPACK) {
            int col = c0 + n * 16 + llo;  // consumer K = 256
            size_t off = (size_t)(R >> 7) * 32768 + (col >> 5) * 4096 +
                         ((R >> 4) & 7) * 512 + ((col >> 3) & 3) * 128 +
                         (R & 15) * 8 + (col & 7);
            Hout[off] = f2b(v);
          } else {
            Hout[(size_t)R * HPITCH + HOFF + c0 + n * 16 + llo] = f2b(v);
          }
        }
      }
    }
  } else {
    float b1v[8], w2v[8];
#pragma unroll
    for (int n = 0; n < 8; ++n) {
      b1v[n] = bias[n * 16 + llo];
      w2v[n] = w2[n * 16 + llo];
    }
    float bf2v = bf2p[0];
#pragma unroll
    for (int mi = 0; mi < 2; ++mi) {
#pragma unroll
      for (int r = 0; r < 4; ++r) {
        float s = 0.f;
#pragma unroll
        for (int n = 0; n < 8; ++n) {
          f32x4 av = mi ? acc1[n] : acc0[n];
          s += fmaxf(av[r] + b1v[n], 0.f) * w2v[n];
        }
        s += __shfl_xor(s, 1);
        s += __shfl_xor(s, 2);
        s += __shfl_xor(s, 4);
        s += __shfl_xor(s, 8);
        int R = m0 + (w * 2 + mi) * 16 + lhi * 4 + r;
        if (llo == 0 && R < NN) out[R] = s + bf2v;
      }
    }
  }
}

extern "C" void kernel_launch(void* const* d_in, const int* in_sizes, int n_in,
                              void* d_out, int out_size, void* d_ws, size_t ws_size,
                              hipStream_t stream) {
  const float* x   = (const float*)d_in[0];
  const int*   ei  = (const int*)d_in[1];
  const float* W1l = (const float*)d_in[2];
  const float* b1  = (const float*)d_in[3];
  const float* W1r = (const float*)d_in[4];
  const float* W2l = (const float*)d_in[5];
  const float* b2  = (const float*)d_in[6];
  const float* W2r = (const float*)d_in[7];
  const float* Wf1 = (const float*)d_in[8];
  const float* bf1 = (const float*)d_in[9];
  const float* Wf2 = (const float*)d_in[10];
  const float* bf2 = (const float*)d_in[11];
  float* out = (float*)d_out;

  char* ws = (char*)d_ws;
  size_t o = 0;
  int* deg = (int*)(ws + o); o += 400384;   // zeroed each call
  int* cur = (int*)(ws + o); o += 400384;   // zeroed each call
  size_t zero_bytes = o;
  int* row  = (int*)(ws + o); o += 400640;  // NN+1
  int* aux  = (int*)(ws + o); o += 4096;
  int* eidx = (int*)(ws + o); o += 2400000;
  unsigned short* A1 = (unsigned short*)(ws + o); o += (size_t)MPAD * 256 * 2; // [mean1|x] row-major
  unsigned short* A2 = (unsigned short*)(ws + o); o += (size_t)MPAD * 512 * 2; // [mean2|h1] row-major
  unsigned short* h2 = (unsigned short*)(ws + o); o += (size_t)MPAD * 256 * 2; // PACKED
  unsigned short* W1b  = (unsigned short*)(ws + o); o += 131072;  // PACKED
  unsigned short* W2b  = (unsigned short*)(ws + o); o += 262144;  // PACKED
  unsigned short* Wf1b = (unsigned short*)(ws + o); o += 65536;   // PACKED
  // total ~202 MB

  hipMemsetAsync(d_ws, 0, zero_bytes, stream);

  // CSR build (deterministic per call)
  hist_kernel<<<2048, 256, 0, stream>>>(ei, deg);
  scan1_kernel<<<NBLK, 256, 0, stream>>>(deg, row, aux);
  scan2_kernel<<<1, 256, 0, stream>>>(aux);
  scan3_kernel<<<(NN + 255) / 256, 256, 0, stream>>>(row, aux);
  fill_kernel<<<2048, 256, 0, stream>>>(ei, row, cur, eidx);

  // convert inputs/weights to bf16 operand layouts
  conv_x<<<(NN * 32 + 255) / 256, 256, 0, stream>>>(x, A1);
  conv_w<<<112, 256, 0, stream>>>(W1l, W1r, W2l, W2r, Wf1, W1b, W2b, Wf1b);

  // pipeline (1D grids; GY=2 GEMMs use the XCD-pair swizzle internally)
  agg1_csr<<<25000, 256, 0, stream>>>(A1, row, eidx);
  gemm_kernel<256, 256, 0, 0, 256, 0, 2><<<NT * 2, 256, 0, stream>>>(
      A1, W1b, b1, nullptr, nullptr, A2, 512, 256, nullptr);
  agg2_csr<<<25000, 256, 0, stream>>>(A2, row, eidx);
  gemm_kernel<512, 512, 0, 0, 256, 1, 2><<<NT * 2, 256, 0, stream>>>(
      A2, W2b, b2, nullptr, nullptr, h2, 0, 0, nullptr);
  gemm_kernel<256, 256, 1, 1, 128, 0, 1><<<NT, 256, 0, stream>>>(
      h2, Wf1b, bf1, Wf2, bf2, nullptr, 0, 0, out);
}